// Round 4
// baseline (635.152 us; speedup 1.0000x reference)
//
#include <hip/hip_runtime.h>
#include <math.h>

#define BATCH 8
#define CH 512
#define HW 16384
#define NS 3
#define HD 1024
#define KSEL 256

// ---------------- Kernel 1: per-(b,c) stats: std, median, max ----------------
// One block per (b,c) row of 16384 floats. 256 threads, 64 floats/thread in
// registers. sum/sumsq in f64. Exact median via 8-bit radix select on
// order-transformed uint keys (16 LDS sub-histograms to reduce atomic
// contention), ranks 8191 and 8192 averaged.

__device__ inline float key_to_float(unsigned int key) {
    unsigned int u = (key & 0x80000000u) ? (key ^ 0x80000000u) : ~key;
    return __uint_as_float(u);
}

__global__ __launch_bounds__(256) void stats_kernel(const float* __restrict__ x,
                                                    double* __restrict__ stats) {
    const int row = blockIdx.x;          // b*CH + c
    const int t = threadIdx.x;
    const int lane = t & 63, wid = t >> 6;

    __shared__ unsigned int hist[16 * 257];   // 16 sub-histograms, padded
    __shared__ unsigned int cnt[256];
    __shared__ double s_red[3][4];            // sum, sumsq, max partials per wave
    __shared__ unsigned int s_prefix, s_rank;
    __shared__ int s_cntle[4];
    __shared__ unsigned int s_mgt[4];

    const float4* xr = (const float4*)(x + (size_t)row * HW);

    unsigned int kv[64];
    double sum = 0.0, sumsq = 0.0;
    float mx = -INFINITY;

    #pragma unroll
    for (int i = 0; i < 16; ++i) {
        float4 f = xr[i * 256 + t];
        float c0 = f.x, c1 = f.y, c2 = f.z, c3 = f.w;
        sum += (double)c0 + (double)c1 + (double)c2 + (double)c3;
        sumsq += (double)c0 * (double)c0 + (double)c1 * (double)c1
               + (double)c2 * (double)c2 + (double)c3 * (double)c3;
        mx = fmaxf(mx, fmaxf(fmaxf(c0, c1), fmaxf(c2, c3)));
        unsigned int u0 = __float_as_uint(c0);
        unsigned int u1 = __float_as_uint(c1);
        unsigned int u2 = __float_as_uint(c2);
        unsigned int u3 = __float_as_uint(c3);
        kv[i * 4 + 0] = u0 ^ ((u0 & 0x80000000u) ? 0xFFFFFFFFu : 0x80000000u);
        kv[i * 4 + 1] = u1 ^ ((u1 & 0x80000000u) ? 0xFFFFFFFFu : 0x80000000u);
        kv[i * 4 + 2] = u2 ^ ((u2 & 0x80000000u) ? 0xFFFFFFFFu : 0x80000000u);
        kv[i * 4 + 3] = u3 ^ ((u3 & 0x80000000u) ? 0xFFFFFFFFu : 0x80000000u);
    }

    // wave reduce sum/sumsq/max
    #pragma unroll
    for (int off = 32; off; off >>= 1) {
        sum += __shfl_down(sum, off);
        sumsq += __shfl_down(sumsq, off);
        float o = __shfl_down(mx, off);
        mx = fmaxf(mx, o);
    }
    if (lane == 0) { s_red[0][wid] = sum; s_red[1][wid] = sumsq; s_red[2][wid] = (double)mx; }

    // ---- radix select for rank 8191 (0-indexed) ----
    unsigned int prefix = 0;
    int rank = 8191;
    unsigned int* myh = &hist[(t & 15) * 257];

    for (int p = 0; p < 4; ++p) {
        const int shift = 24 - 8 * p;
        for (int i = t; i < 16 * 257; i += 256) hist[i] = 0;
        __syncthreads();
        const unsigned int himask = (p == 0) ? 0u : (0xFFFFFFFFu << (32 - 8 * p));
        #pragma unroll
        for (int i = 0; i < 64; ++i) {
            unsigned int key = kv[i];
            if ((key & himask) == prefix) atomicAdd(&myh[(key >> shift) & 255], 1u);
        }
        __syncthreads();
        if (t < 256) {
            unsigned int c = 0;
            #pragma unroll
            for (int h = 0; h < 16; ++h) c += hist[h * 257 + t];
            cnt[t] = c;
        }
        __syncthreads();
        if (t == 0) {
            int r = rank;
            unsigned int b = 0;
            for (b = 0; b < 256; ++b) {
                unsigned int c = cnt[b];
                if ((unsigned int)r < c) break;
                r -= (int)c;
            }
            s_prefix = prefix | (b << shift);
            s_rank = (unsigned int)r;
        }
        __syncthreads();
        prefix = s_prefix;
        rank = (int)s_rank;
        __syncthreads();
    }

    const unsigned int k1 = prefix;   // key of a[8191]

    // count <= k1 and min key > k1 (to get a[8192])
    int cntle = 0;
    unsigned int mgt = 0xFFFFFFFFu;
    #pragma unroll
    for (int i = 0; i < 64; ++i) {
        unsigned int key = kv[i];
        if (key <= k1) cntle++;
        else if (key < mgt) mgt = key;
    }
    #pragma unroll
    for (int off = 32; off; off >>= 1) {
        cntle += __shfl_down(cntle, off);
        unsigned int o = __shfl_down(mgt, off);
        if (o < mgt) mgt = o;
    }
    if (lane == 0) { s_cntle[wid] = cntle; s_mgt[wid] = mgt; }
    __syncthreads();

    if (t == 0) {
        double sum_t = s_red[0][0] + s_red[0][1] + s_red[0][2] + s_red[0][3];
        double sq_t  = s_red[1][0] + s_red[1][1] + s_red[1][2] + s_red[1][3];
        double mx_t = fmax(fmax(s_red[2][0], s_red[2][1]), fmax(s_red[2][2], s_red[2][3]));
        int cle = s_cntle[0] + s_cntle[1] + s_cntle[2] + s_cntle[3];
        unsigned int mg = s_mgt[0];
        if (s_mgt[1] < mg) mg = s_mgt[1];
        if (s_mgt[2] < mg) mg = s_mgt[2];
        if (s_mgt[3] < mg) mg = s_mgt[3];

        unsigned int k2 = (cle >= 8193) ? k1 : mg;
        double med = 0.5 * ((double)key_to_float(k1) + (double)key_to_float(k2));
        double mean = sum_t / (double)HW;
        double var = sq_t / (double)HW - mean * mean;
        if (var < 0.0) var = 0.0;

        stats[0 * (BATCH * CH) + row] = sqrt(var);
        stats[1 * (BATCH * CH) + row] = med;
        stats[2 * (BATCH * CH) + row] = mx_t;
    }
}

// ---------------- Kernel 2: h = relu(stats @ W1 + b1), f64 accumulate ----------------
// grid = NS*BATCH*4 blocks; each block computes 256 of the 1024 hidden units.
__global__ __launch_bounds__(256) void mlp1_kernel(const double* __restrict__ stats,
                                                   const float* __restrict__ W1,
                                                   const float* __restrict__ b1,
                                                   double* __restrict__ h) {
    const int bid = blockIdx.x;       // ((s*BATCH)+b)*4 + jc
    const int jc = bid & 3, sb = bid >> 2;
    const int s = sb >> 3, b = sb & 7;
    const int t = threadIdx.x;
    const int j = jc * 256 + t;

    __shared__ double st[CH];
    st[t] = stats[s * (BATCH * CH) + b * CH + t];
    st[t + 256] = stats[s * (BATCH * CH) + b * CH + t + 256];
    __syncthreads();

    double acc = (double)b1[s * HD + j];
    const float* w = W1 + (size_t)s * CH * HD + j;
    for (int c = 0; c < CH; ++c) acc += st[c] * (double)w[(size_t)c * HD];
    h[(size_t)sb * HD + j] = acc > 0.0 ? acc : 0.0;
}

// ---------------- Kernel 3: logits = h @ W2 + b2, f64 accumulate ----------------
// grid = NS*BATCH*2 blocks; each block computes 256 of the 512 channels.
__global__ __launch_bounds__(256) void mlp2_kernel(const double* __restrict__ h,
                                                   const float* __restrict__ W2,
                                                   const float* __restrict__ b2,
                                                   double* __restrict__ logits) {
    const int bid = blockIdx.x;       // sb*2 + cc
    const int cc = bid & 1, sb = bid >> 1;
    const int s = sb >> 3;
    const int t = threadIdx.x;
    const int c = cc * 256 + t;

    __shared__ double hh[HD];
    #pragma unroll
    for (int i = 0; i < 4; ++i) hh[t + i * 256] = h[(size_t)sb * HD + t + i * 256];
    __syncthreads();

    double acc = (double)b2[s * CH + c];
    const float* w = W2 + (size_t)s * HD * CH + c;
    for (int j = 0; j < HD; ++j) acc += hh[j] * (double)w[(size_t)j * CH];
    logits[(size_t)sb * CH + c] = acc;
}

// ---------------- Kernel 4: rank channels per batch (JAX top_k semantics) ----------------
// softmax(mean_s logits) is monotone in sum_s logits, so rank by the sum.
// Tie-break: equal value -> lower index first (matches jax.lax.top_k).
__global__ __launch_bounds__(512) void rank_kernel(const double* __restrict__ logits,
                                                   int* __restrict__ sel) {
    const int b = blockIdx.x, t = threadIdx.x;   // t = channel
    __shared__ double L[CH];
    L[t] = logits[(0 * BATCH + b) * CH + t]
         + logits[(1 * BATCH + b) * CH + t]
         + logits[(2 * BATCH + b) * CH + t];
    __syncthreads();
    const double Li = L[t];
    int rank = 0;
    for (int j = 0; j < CH; ++j) {
        double Lj = L[j];
        rank += (Lj > Li) || (Lj == Li && j < t);
    }
    if (rank < KSEL) sel[b * KSEL + rank] = t;
}

// ---------------- Kernel 5: gather selected channels ----------------
__global__ __launch_bounds__(256) void gather_kernel(const float* __restrict__ x,
                                                     const int* __restrict__ sel,
                                                     float* __restrict__ out) {
    const int blk = blockIdx.x;       // b*KSEL + k
    const int b = blk >> 8;
    const int ch = sel[blk];
    const float4* src = (const float4*)(x + ((size_t)b * CH + ch) * HW);
    float4* dst = (float4*)(out + (size_t)blk * HW);
    const int t = threadIdx.x;
    #pragma unroll
    for (int i = 0; i < 16; ++i) dst[i * 256 + t] = src[i * 256 + t];
}

extern "C" void kernel_launch(void* const* d_in, const int* in_sizes, int n_in,
                              void* d_out, int out_size, void* d_ws, size_t ws_size,
                              hipStream_t stream) {
    const float* x  = (const float*)d_in[0];
    const float* W1 = (const float*)d_in[1];
    const float* b1 = (const float*)d_in[2];
    const float* W2 = (const float*)d_in[3];
    const float* b2 = (const float*)d_in[4];
    float* out = (float*)d_out;

    char* ws = (char*)d_ws;
    double* stats  = (double*)(ws);                              // 3*4096 f64   =  96 KiB
    double* h      = (double*)(ws + 98304);                      // 24*1024 f64  = 192 KiB
    double* logits = (double*)(ws + 98304 + 196608);             // 24*512 f64   =  96 KiB
    int*    sel    = (int*)   (ws + 98304 + 196608 + 98304);     // 8*256 int    =   8 KiB

    stats_kernel<<<BATCH * CH, 256, 0, stream>>>(x, stats);
    mlp1_kernel<<<NS * BATCH * 4, 256, 0, stream>>>(stats, W1, b1, h);
    mlp2_kernel<<<NS * BATCH * 2, 256, 0, stream>>>(h, W2, b2, logits);
    rank_kernel<<<BATCH, 512, 0, stream>>>(logits, sel);
    gather_kernel<<<BATCH * KSEL, 256, 0, stream>>>(x, sel, out);
}

// Round 8
// 574.864 us; speedup vs baseline: 1.1049x; 1.1049x over previous
//
#include <hip/hip_runtime.h>
#include <math.h>

#define BATCH 8
#define CH 512
#define HW 16384
#define NS 3
#define HD 1024
#define KSEL 256
#define CSPLIT 4   // mlp1 c-split (128 c per block)
#define HSPLIT 8   // mlp2 h-split (128 h per block)

// ---------------- Kernel 1: per-(b,c) stats: std, median, max ----------------
// One block per (b,c) row of 16384 floats. 256 threads, 64 floats/thread held
// in REGISTERS — __launch_bounds__(256,4) caps occupancy at 4 waves/EU so the
// allocator has 128 VGPRs and does not spill kv[64] (round-4 profile showed
// VGPR_Count=48 => full spill to scratch, 214us at 627 GB/s).
// Exact median via 8-bit radix select, ranks 8191/8192 averaged.

__device__ inline float key_to_float(unsigned int key) {
    unsigned int u = (key & 0x80000000u) ? (key ^ 0x80000000u) : ~key;
    return __uint_as_float(u);
}

__global__ __launch_bounds__(256, 4) void stats_kernel(const float* __restrict__ x,
                                                       double* __restrict__ stats) {
    const int row = blockIdx.x;          // b*CH + c
    const int t = threadIdx.x;
    const int lane = t & 63, wid = t >> 6;

    __shared__ unsigned int hist[16 * 257];   // 16 sub-histograms, padded
    __shared__ unsigned int cnt[256];
    __shared__ double s_red[3][4];            // sum, sumsq, max partials per wave
    __shared__ unsigned int s_prefix, s_rank;
    __shared__ int s_cntle[4];
    __shared__ unsigned int s_mgt[4];

    const float4* xr = (const float4*)(x + (size_t)row * HW);

    unsigned int kv[64];
    double sum = 0.0, sumsq = 0.0;
    float mx = -INFINITY;

    #pragma unroll
    for (int i = 0; i < 16; ++i) {
        float4 f = xr[i * 256 + t];
        float c0 = f.x, c1 = f.y, c2 = f.z, c3 = f.w;
        sum += (double)c0 + (double)c1 + (double)c2 + (double)c3;
        sumsq += (double)c0 * (double)c0 + (double)c1 * (double)c1
               + (double)c2 * (double)c2 + (double)c3 * (double)c3;
        mx = fmaxf(mx, fmaxf(fmaxf(c0, c1), fmaxf(c2, c3)));
        unsigned int u0 = __float_as_uint(c0);
        unsigned int u1 = __float_as_uint(c1);
        unsigned int u2 = __float_as_uint(c2);
        unsigned int u3 = __float_as_uint(c3);
        kv[i * 4 + 0] = u0 ^ ((u0 & 0x80000000u) ? 0xFFFFFFFFu : 0x80000000u);
        kv[i * 4 + 1] = u1 ^ ((u1 & 0x80000000u) ? 0xFFFFFFFFu : 0x80000000u);
        kv[i * 4 + 2] = u2 ^ ((u2 & 0x80000000u) ? 0xFFFFFFFFu : 0x80000000u);
        kv[i * 4 + 3] = u3 ^ ((u3 & 0x80000000u) ? 0xFFFFFFFFu : 0x80000000u);
    }

    // wave reduce sum/sumsq/max
    #pragma unroll
    for (int off = 32; off; off >>= 1) {
        sum += __shfl_down(sum, off);
        sumsq += __shfl_down(sumsq, off);
        float o = __shfl_down(mx, off);
        mx = fmaxf(mx, o);
    }
    if (lane == 0) { s_red[0][wid] = sum; s_red[1][wid] = sumsq; s_red[2][wid] = (double)mx; }

    // ---- radix select for rank 8191 (0-indexed) ----
    unsigned int prefix = 0;
    int rank = 8191;
    unsigned int* myh = &hist[(t & 15) * 257];

    for (int p = 0; p < 4; ++p) {
        const int shift = 24 - 8 * p;
        for (int i = t; i < 16 * 257; i += 256) hist[i] = 0;
        __syncthreads();
        const unsigned int himask = (p == 0) ? 0u : (0xFFFFFFFFu << (32 - 8 * p));
        #pragma unroll
        for (int i = 0; i < 64; ++i) {
            unsigned int key = kv[i];
            if ((key & himask) == prefix) atomicAdd(&myh[(key >> shift) & 255], 1u);
        }
        __syncthreads();
        if (t < 256) {
            unsigned int c = 0;
            #pragma unroll
            for (int h = 0; h < 16; ++h) c += hist[h * 257 + t];
            cnt[t] = c;
        }
        __syncthreads();
        if (t == 0) {
            int r = rank;
            unsigned int b = 0;
            for (b = 0; b < 256; ++b) {
                unsigned int c = cnt[b];
                if ((unsigned int)r < c) break;
                r -= (int)c;
            }
            s_prefix = prefix | (b << shift);
            s_rank = (unsigned int)r;
        }
        __syncthreads();
        prefix = s_prefix;
        rank = (int)s_rank;
        __syncthreads();
    }

    const unsigned int k1 = prefix;   // key of a[8191]

    // count <= k1 and min key > k1 (to get a[8192])
    int cntle = 0;
    unsigned int mgt = 0xFFFFFFFFu;
    #pragma unroll
    for (int i = 0; i < 64; ++i) {
        unsigned int key = kv[i];
        if (key <= k1) cntle++;
        else if (key < mgt) mgt = key;
    }
    #pragma unroll
    for (int off = 32; off; off >>= 1) {
        cntle += __shfl_down(cntle, off);
        unsigned int o = __shfl_down(mgt, off);
        if (o < mgt) mgt = o;
    }
    if (lane == 0) { s_cntle[wid] = cntle; s_mgt[wid] = mgt; }
    __syncthreads();

    if (t == 0) {
        double sum_t = s_red[0][0] + s_red[0][1] + s_red[0][2] + s_red[0][3];
        double sq_t  = s_red[1][0] + s_red[1][1] + s_red[1][2] + s_red[1][3];
        double mx_t = fmax(fmax(s_red[2][0], s_red[2][1]), fmax(s_red[2][2], s_red[2][3]));
        int cle = s_cntle[0] + s_cntle[1] + s_cntle[2] + s_cntle[3];
        unsigned int mg = s_mgt[0];
        if (s_mgt[1] < mg) mg = s_mgt[1];
        if (s_mgt[2] < mg) mg = s_mgt[2];
        if (s_mgt[3] < mg) mg = s_mgt[3];

        unsigned int k2 = (cle >= 8193) ? k1 : mg;
        double med = 0.5 * ((double)key_to_float(k1) + (double)key_to_float(k2));
        double mean = sum_t / (double)HW;
        double var = sq_t / (double)HW - mean * mean;
        if (var < 0.0) var = 0.0;

        stats[0 * (BATCH * CH) + row] = sqrt(var);
        stats[1 * (BATCH * CH) + row] = med;
        stats[2 * (BATCH * CH) + row] = mx_t;
    }
}

// ---------------- Kernel 2: hpart[cc][sb][j] = sum_{c in cc-range} st[c]*W1[c][j] ----
// c-split into 4 ranges of 128 -> 384 blocks (was 96). Bias+relu folded into mlp2.
__global__ __launch_bounds__(256) void mlp1_kernel(const double* __restrict__ stats,
                                                   const float* __restrict__ W1,
                                                   double* __restrict__ hpart) {
    const int bid = blockIdx.x;                 // ((cc*NS*BATCH) + sb)*4 + jc
    const int jc = bid & 3;
    const int sb = (bid >> 2) % (NS * BATCH);
    const int cc = bid / (4 * NS * BATCH);
    const int s = sb / BATCH, b = sb % BATCH;
    const int t = threadIdx.x;
    const int j = jc * 256 + t;

    __shared__ double st[128];
    if (t < 128) st[t] = stats[s * (BATCH * CH) + b * CH + cc * 128 + t];
    __syncthreads();

    double a0 = 0.0, a1 = 0.0;
    const float* w = W1 + (size_t)s * CH * HD + (size_t)(cc * 128) * HD + j;
    #pragma unroll 4
    for (int c = 0; c < 128; c += 2) {
        a0 += st[c]     * (double)w[(size_t)c * HD];
        a1 += st[c + 1] * (double)w[(size_t)(c + 1) * HD];
    }
    hpart[((size_t)cc * (NS * BATCH) + sb) * HD + j] = a0 + a1;
}

// ---------------- Kernel 3: lpart[hc][sb][c] = sum_{h in hc-range} relu-h[h]*W2[h][c] ----
// h-split into 8 ranges of 128 -> 384 blocks (was 48). b2 folded into rank.
__global__ __launch_bounds__(256) void mlp2_kernel(const double* __restrict__ hpart,
                                                   const float* __restrict__ b1,
                                                   const float* __restrict__ W2,
                                                   double* __restrict__ lpart) {
    const int bid = blockIdx.x;                 // ((hc*NS*BATCH) + sb)*2 + cq
    const int cq = bid & 1;
    const int sb = (bid >> 1) % (NS * BATCH);
    const int hc = bid / (2 * NS * BATCH);
    const int s = sb / BATCH;
    const int t = threadIdx.x;
    const int c = cq * 256 + t;

    __shared__ double hh[128];
    if (t < 128) {
        const int j = hc * 128 + t;
        double v = (double)b1[s * HD + j];
        #pragma unroll
        for (int cc = 0; cc < CSPLIT; ++cc)
            v += hpart[((size_t)cc * (NS * BATCH) + sb) * HD + j];
        hh[t] = v > 0.0 ? v : 0.0;
    }
    __syncthreads();

    double a0 = 0.0, a1 = 0.0;
    const float* w = W2 + (size_t)s * HD * CH + (size_t)(hc * 128) * CH + c;
    #pragma unroll 4
    for (int h = 0; h < 128; h += 2) {
        a0 += hh[h]     * (double)w[(size_t)h * CH];
        a1 += hh[h + 1] * (double)w[(size_t)(h + 1) * CH];
    }
    lpart[((size_t)hc * (NS * BATCH) + sb) * CH + c] = a0 + a1;
}

// ---------------- Kernel 4: rank channels per batch (JAX top_k semantics) ----------------
// softmax(mean_s logits) is monotone in sum_s logits, so rank by the sum.
// Tie-break: equal value -> lower index first (matches jax.lax.top_k).
__global__ __launch_bounds__(512) void rank_kernel(const double* __restrict__ lpart,
                                                   const float* __restrict__ b2,
                                                   int* __restrict__ sel) {
    const int b = blockIdx.x, t = threadIdx.x;   // t = channel
    __shared__ double L[CH];
    double v = 0.0;
    #pragma unroll
    for (int s = 0; s < NS; ++s) {
        double vs = (double)b2[s * CH + t];
        const int sb = s * BATCH + b;
        #pragma unroll
        for (int hc = 0; hc < HSPLIT; ++hc)
            vs += lpart[((size_t)hc * (NS * BATCH) + sb) * CH + t];
        v += vs;
    }
    L[t] = v;
    __syncthreads();
    const double Li = L[t];
    int rank = 0;
    for (int j = 0; j < CH; ++j) {
        double Lj = L[j];
        rank += (Lj > Li) || (Lj == Li && j < t);
    }
    if (rank < KSEL) sel[b * KSEL + rank] = t;
}

// ---------------- Kernel 5: gather selected channels ----------------
__global__ __launch_bounds__(256) void gather_kernel(const float* __restrict__ x,
                                                     const int* __restrict__ sel,
                                                     float* __restrict__ out) {
    const int blk = blockIdx.x;       // b*KSEL + k
    const int b = blk >> 8;
    const int ch = sel[blk];
    const float4* src = (const float4*)(x + ((size_t)b * CH + ch) * HW);
    float4* dst = (float4*)(out + (size_t)blk * HW);
    const int t = threadIdx.x;
    #pragma unroll
    for (int i = 0; i < 16; ++i) dst[i * 256 + t] = src[i * 256 + t];
}

extern "C" void kernel_launch(void* const* d_in, const int* in_sizes, int n_in,
                              void* d_out, int out_size, void* d_ws, size_t ws_size,
                              hipStream_t stream) {
    const float* x  = (const float*)d_in[0];
    const float* W1 = (const float*)d_in[1];
    const float* b1 = (const float*)d_in[2];
    const float* W2 = (const float*)d_in[3];
    const float* b2 = (const float*)d_in[4];
    float* out = (float*)d_out;

    char* ws = (char*)d_ws;
    double* stats  = (double*)(ws);                    // 3*4096 f64          =  96 KiB
    double* hpart  = (double*)(ws + (96 << 10));       // 4*24*1024 f64       = 768 KiB
    double* lpart  = (double*)(ws + (96 << 10) + (768 << 10));               // 768 KiB
    int*    sel    = (int*)   (ws + (96 << 10) + (768 << 10) + (768 << 10)); //   8 KiB

    stats_kernel<<<BATCH * CH, 256, 0, stream>>>(x, stats);
    mlp1_kernel<<<CSPLIT * NS * BATCH * 4, 256, 0, stream>>>(stats, W1, hpart);
    mlp2_kernel<<<HSPLIT * NS * BATCH * 2, 256, 0, stream>>>(hpart, b1, W2, lpart);
    rank_kernel<<<BATCH, 512, 0, stream>>>(lpart, b2, sel);
    gather_kernel<<<BATCH * KSEL, 256, 0, stream>>>(x, sel, out);
}